// Round 11
// baseline (94.295 us; speedup 1.0000x reference)
//
#include <hip/hip_runtime.h>
#include <hip/hip_bf16.h>
#include <stdint.h>

#define BATCH  8
#define SEQ    4096
#define DK     64
#define DMODEL 512
#define QBLK   64
#define KBLK   64
#define NT     256

#define KWS_OFF   0u
#define VWS_OFF   4194304u
#define WWS_OFF   8388608u
#define WS_NEED   8454144u
#define POFF      8454144u
// split-K x2 (R8 layout): opart 2*8*4096*64*4 = 16777216, lpart 2*8*4096*4
#define LOFF2     (POFF + 16777216u)
#define WS_NEED2  (LOFF2 + 262144u)
// split-K x4: opart 4*8*4096*64*4 = 33554432, lpart 4*8*4096*4 = 524288
#define LOFF4     (POFF + 33554432u)
#define WS_NEED3  (LOFF4 + 524288u)

typedef __attribute__((ext_vector_type(8)))  short short8;
typedef __attribute__((ext_vector_type(4)))  float f32x4;
typedef __attribute__((ext_vector_type(16))) float f32x16;

__device__ __forceinline__ unsigned short f2bf(float x) {
  uint32_t u = __builtin_bit_cast(uint32_t, x);
  u += 0x7FFFu + ((u >> 16) & 1u);          // RNE
  return (unsigned short)(u >> 16);
}
__device__ __forceinline__ uint32_t pack2(float a, float b) {
  return (uint32_t)f2bf(a) | ((uint32_t)f2bf(b) << 16);
}
__device__ __forceinline__ uint32_t cvtpk2(float a, float b) {
  __hip_bfloat162 h = __float22bfloat162_rn(make_float2(a, b)); // v_cvt_pk_bf16_f32
  uint32_t r;
  __builtin_memcpy(&r, &h, 4);
  return r;
}
__device__ __forceinline__ void async16(void* lds, const void* g) {
  __builtin_amdgcn_global_load_lds(
      (const __attribute__((address_space(1))) uint32_t*)g,
      (__attribute__((address_space(3))) uint32_t*)lds, 16, 0, 0);
}

// ============================================================================
// Pre-pass (EXACT R8, hardware-verified): K -> bf16 swizzled tile images,
// V -> bf16 transposed swizzled tile images, W -> bf16 W^T chunk images.
// ============================================================================
__global__ __launch_bounds__(256)
void preconv(const float* __restrict__ kg_, const float* __restrict__ vg_,
             const float* __restrict__ wg_, unsigned char* __restrict__ ws) {
  int id = blockIdx.x * 256 + threadIdx.x;
  unsigned char* kws = ws + KWS_OFF;
  unsigned char* vws = ws + VWS_OFF;
  unsigned char* wws = ws + WWS_OFF;
  if (id < 262144) {
    int dg = id & 7, key = (id >> 3) & 63, t = (id >> 9) & 63, b = id >> 15;
    const float* src = kg_ + (((size_t)(b * 4096 + t * 64 + key)) << 6) + dg * 8;
    float4 a0 = *(const float4*)src;
    float4 a1 = *(const float4*)(src + 4);
    uint4 o;
    o.x = pack2(a0.x, a0.y); o.y = pack2(a0.z, a0.w);
    o.z = pack2(a1.x, a1.y); o.w = pack2(a1.z, a1.w);
    *(uint4*)(kws + (((size_t)(b * 64 + t)) << 13) +
              (uint32_t)(key * 128 + ((dg * 16) ^ ((key & 7) << 4)))) = o;
  } else if (id < 524288) {
    int iv = id - 262144;
    int kg2 = iv & 7, d = (iv >> 3) & 63, t = (iv >> 9) & 63, b = iv >> 15;
    const float* src = vg_ + (((size_t)(b * 4096 + t * 64 + kg2 * 8)) << 6) + d;
    float m[8];
    #pragma unroll
    for (int i = 0; i < 8; ++i) m[i] = src[i * 64];
    uint4 o;
    o.x = pack2(m[0], m[1]); o.y = pack2(m[2], m[3]);
    o.z = pack2(m[4], m[5]); o.w = pack2(m[6], m[7]);
    *(uint4*)(vws + (((size_t)(b * 64 + t)) << 13) +
              (uint32_t)(d * 128 + ((kg2 * 16) ^ ((d & 7) << 4)))) = o;
  } else if (id < 528384) {
    int iw = id - 524288;
    int kg2 = iw & 7, n = (iw >> 3) & 127, c = iw >> 10;
    const float* src = wg_ + (size_t)(kg2 * 8) * DMODEL + c * 128 + n;
    float m[8];
    #pragma unroll
    for (int i = 0; i < 8; ++i) m[i] = src[i * DMODEL];
    uint4 o;
    o.x = pack2(m[0], m[1]); o.y = pack2(m[2], m[3]);
    o.z = pack2(m[4], m[5]); o.w = pack2(m[6], m[7]);
    *(uint4*)(wws + c * 16384 + (uint32_t)(n * 128 + ((kg2 * 16) ^ ((n & 7) << 4)))) = o;
  }
}

// ============================================================================
// Split-K attention (EXACT R8 body; only the z-extent is now a runtime param).
// 32x32 MFMA, swapped QK^T, P fully in registers via cvt_pk + permlane32_swap.
// grid (8, 32, NSPLIT); block z covers `ntiles` K-tiles.
// ============================================================================
struct SMemA32 { unsigned char kt[2][8192]; unsigned char vt[2][8192]; };
static_assert(sizeof(SMemA32) == 32768, "LDS layout");

__global__ __launch_bounds__(NT, 2)
void attn_split32(const float* __restrict__ qg, const unsigned char* __restrict__ ws,
                  float* __restrict__ opart, float* __restrict__ lpart, int ntiles) {
  __shared__ SMemA32 sm;
  const int b    = blockIdx.x;      // batch -> XCD (linear id % 8 == b)
  const int qb   = blockIdx.y;
  const int z    = blockIdx.z;      // K-split slice
  const int tid  = threadIdx.x;
  const int wid  = tid >> 6;
  const int lane = tid & 63;
  const int l31  = lane & 31;
  const int hi   = lane >> 5;

  const unsigned char* kws = ws + KWS_OFF;
  const unsigned char* vws = ws + VWS_OFF;
  const int    wstg  = wid << 11;          // each wave stages 2KB of each tile
  const int    ln16  = lane << 4;
  const size_t tbase = ((size_t)(b * 64)) << 13;
  const int    tt0   = z * ntiles;

  const float SC = 0.125f * 1.44269504088896f;   // scale * log2(e)

  // ---- Q^T B-fragments (B: k=d=(ds*16 + hi*8 + e), col=q=l31), scaled ----
  const int qrow = qb * 128 + wid * 32 + l31;
  short8 qf[4];
  {
    const float* qp = qg + ((size_t)b * SEQ + qrow) * DK;
    #pragma unroll
    for (int ds = 0; ds < 4; ++ds) {
      const float* p = qp + ds * 16 + hi * 8;
      float4 a0 = *(const float4*)p;
      float4 a1 = *(const float4*)(p + 4);
      union { short8 v; uint32_t u[4]; } cv;
      cv.u[0] = cvtpk2(a0.x * SC, a0.y * SC); cv.u[1] = cvtpk2(a0.z * SC, a0.w * SC);
      cv.u[2] = cvtpk2(a1.x * SC, a1.y * SC); cv.u[3] = cvtpk2(a1.z * SC, a1.w * SC);
      qf[ds] = cv.v;
    }
  }

  f32x16 o0, o1;
  #pragma unroll
  for (int r = 0; r < 16; ++r) { o0[r] = 0.f; o1[r] = 0.f; }
  float lsum = 0.f;

#define STG32(buf, tt) do { \
    const unsigned char* ks_ = kws + tbase + (((size_t)(tt)) << 13); \
    const unsigned char* vs_ = vws + tbase + (((size_t)(tt)) << 13); \
    async16(sm.kt[buf] + wstg,        ks_ + wstg + ln16); \
    async16(sm.kt[buf] + wstg + 1024, ks_ + wstg + 1024 + ln16); \
    async16(sm.vt[buf] + wstg,        vs_ + wstg + ln16); \
    async16(sm.vt[buf] + wstg + 1024, vs_ + wstg + 1024 + ln16); \
  } while (0)

  STG32(0, tt0);
  int cur = 0;
  #pragma unroll 1
  for (int t = 0; t < ntiles; ++t) {
    __syncthreads();                 // buf[cur] staged; all waves past buf[cur^1] reads
    if (t + 1 < ntiles) STG32(cur ^ 1, tt0 + t + 1);

    const char* ktc = (const char*)sm.kt[cur];
    const char* vtc = (const char*)sm.vt[cur];

    // ---- swapped QK^T: sT[kh] = K[kh*32+..] . Q^T  (keys in regs, q on lanes)
    f32x16 s0, s1;
    #pragma unroll
    for (int r = 0; r < 16; ++r) { s0[r] = 0.f; s1[r] = 0.f; }
    #pragma unroll
    for (int ds = 0; ds < 4; ++ds) {
      uint32_t cb   = (uint32_t)(ds * 32 + hi * 16);     // d-byte base
      uint32_t swz  = (uint32_t)((l31 & 7) << 4);
      uint32_t off0 = ((uint32_t)l31 << 7)        + (cb ^ swz);
      uint32_t off1 = ((uint32_t)(32 + l31) << 7) + (cb ^ swz);
      short8 ka0 = *(const short8*)(ktc + off0);
      short8 ka1 = *(const short8*)(ktc + off1);
      s0 = __builtin_amdgcn_mfma_f32_32x32x16_bf16(ka0, qf[ds], s0, 0, 0, 0);
      s1 = __builtin_amdgcn_mfma_f32_32x32x16_bf16(ka1, qf[ds], s1, 0, 0, 0);
    }

    // ---- P = exp2(S), per-lane row sums (q=l31, this lane's 32 keys) ----
    #pragma unroll
    for (int r = 0; r < 16; ++r) {
      s0[r] = exp2f(s0[r]); lsum += s0[r];
      s1[r] = exp2f(s1[r]); lsum += s1[r];
    }

    // ---- PV: per 16-key slice ks, build A-frag in-register, 2 d-halves ----
    #pragma unroll
    for (int ks = 0; ks < 4; ++ks) {
      int ss = ks & 1;
      uint32_t A0, A1, B0, B1;
      if (ks < 2) {
        A0 = cvtpk2(s0[8 * ss + 0], s0[8 * ss + 1]);
        A1 = cvtpk2(s0[8 * ss + 2], s0[8 * ss + 3]);
        B0 = cvtpk2(s0[8 * ss + 4], s0[8 * ss + 5]);
        B1 = cvtpk2(s0[8 * ss + 6], s0[8 * ss + 7]);
      } else {
        A0 = cvtpk2(s1[8 * ss + 0], s1[8 * ss + 1]);
        A1 = cvtpk2(s1[8 * ss + 2], s1[8 * ss + 3]);
        B0 = cvtpk2(s1[8 * ss + 4], s1[8 * ss + 5]);
        B1 = cvtpk2(s1[8 * ss + 6], s1[8 * ss + 7]);
      }
      // dst hi-lanes <-> src lo-lanes: yields frag dwords (0,2) and (1,3)
      asm("v_permlane32_swap_b32 %0, %1" : "+v"(A0), "+v"(B0));
      asm("v_permlane32_swap_b32 %0, %1" : "+v"(A1), "+v"(B1));
      union { short8 v; uint32_t u[4]; } pa;
      pa.u[0] = A0; pa.u[1] = A1; pa.u[2] = B0; pa.u[3] = B1;

      uint32_t kb = (uint32_t)(ks * 32 + hi * 16);       // key-byte base
      {
        int d = l31;
        uint32_t off = ((uint32_t)d << 7) + (kb ^ ((uint32_t)(d & 7) << 4));
        short8 vf = *(const short8*)(vtc + off);
        o0 = __builtin_amdgcn_mfma_f32_32x32x16_bf16(pa.v, vf, o0, 0, 0, 0);
      }
      {
        int d = 32 + l31;
        uint32_t off = ((uint32_t)d << 7) + (kb ^ ((uint32_t)(d & 7) << 4));
        short8 vf = *(const short8*)(vtc + off);
        o1 = __builtin_amdgcn_mfma_f32_32x32x16_bf16(pa.v, vf, o1, 0, 0, 0);
      }
    }
    cur ^= 1;
  }

  // ---- partials: O rows in regs (q=(r&3)+8*(r>>2)+4*hi), d on lanes ----
  float lt = lsum + __shfl_xor(lsum, 32, 64);   // both key-halves of q=l31
  const size_t rbase = (size_t)(z * 8 + b) * 4096 + (size_t)(qb * 128 + wid * 32);
  float* op = opart + rbase * 64;
  #pragma unroll
  for (int r = 0; r < 16; ++r) {
    int qloc = (r & 3) + 8 * (r >> 2) + 4 * hi;
    op[(size_t)qloc * 64 + l31]      = o0[r];
    op[(size_t)qloc * 64 + 32 + l31] = o1[r];
  }
  if (hi == 0) lpart[rbase + l31] = lt;
}

// ============================================================================
// Combine + FC kernel: grid (8, 64). Sums nz K-split partials, normalizes,
// then O[64x64] @ W[64x512] + b with dbuf W staging.
// ============================================================================
struct SMemComb {
  unsigned char  wT[2][16384];     // W^T chunk images (dbuf)
  unsigned short ob[4][1024];      // per-wave normalized O [16][64] bf16, swz
};
static_assert(sizeof(SMemComb) == 40960, "LDS layout");

__global__ __launch_bounds__(NT, 2)
void fc_combine(const float* __restrict__ opart, const float* __restrict__ lpart,
                const unsigned char* __restrict__ ws, const float* __restrict__ bg,
                float* __restrict__ outg, int nz) {
  __shared__ SMemComb sm;
  const int b    = blockIdx.x;
  const int qb   = blockIdx.y;
  const int tid  = threadIdx.x;
  const int wid  = tid >> 6;
  const int lane = tid & 63;
  const int l15  = lane & 15;
  const int g    = lane >> 4;
  const int g4   = g << 2;

  const unsigned char* wws = ws + WWS_OFF;
  const int wb   = wid << 10;
  const int ln16 = lane << 4;

  const f32x4 fz = {0.f, 0.f, 0.f, 0.f};

  float inv[4];
  #pragma unroll
  for (int j = 0; j < 4; ++j) {
    int row = wid * 16 + g4 + j;
    float ls = 0.f;
    #pragma unroll 1
    for (int zz = 0; zz < nz; ++zz)
      ls += lpart[(size_t)(zz * 8 + b) * 4096 + qb * 64 + row];
    inv[j] = 1.0f / ls;
  }
  unsigned short* obase = sm.ob[wid];
  #pragma unroll
  for (int dt = 0; dt < 4; ++dt)
    #pragma unroll
    for (int j = 0; j < 4; ++j) {
      int row  = wid * 16 + g4 + j;
      int col  = l15 + dt * 16;
      float o = 0.f;
      #pragma unroll 1
      for (int zz = 0; zz < nz; ++zz)
        o += opart[((size_t)(zz * 8 + b) * 4096 + qb * 64 + row) * 64 + col];
      o *= inv[j];
      int rloc = g4 + j;
      uint32_t off = (uint32_t)(rloc << 7) +
                     ((uint32_t)(col << 1) ^ (uint32_t)((rloc & 7) << 4));
      *(unsigned short*)((char*)obase + off) = f2bf(o);
    }
  short8 af[2];
  #pragma unroll
  for (int ks2 = 0; ks2 < 2; ++ks2) {
    uint32_t off = (uint32_t)(l15 << 7) +
                   ((uint32_t)((g * 8 + ks2 * 32) << 1) ^ (uint32_t)((l15 & 7) << 4));
    af[ks2] = *(const short8*)((const char*)obase + off);
  }

#define STAGE_W(buf, cc) do { \
    const unsigned char* wsrc = wws + (uint32_t)(cc) * 16384u; \
    async16(sm.wT[buf] + wb,         wsrc + wb + ln16); \
    async16(sm.wT[buf] + wb + 4096,  wsrc + wb + 4096 + ln16); \
    async16(sm.wT[buf] + wb + 8192,  wsrc + wb + 8192 + ln16); \
    async16(sm.wT[buf] + wb + 12288, wsrc + wb + 12288 + ln16); \
  } while (0)

  STAGE_W(0, 0);
  const int orow = qb * QBLK + wid * 16;
  #pragma unroll 1
  for (int c = 0; c < 4; ++c) {
    __syncthreads();               // wT[c&1] ready; prev reads of other buf done
    if (c + 1 < 4) STAGE_W((c + 1) & 1, c + 1);
    const char* wtc = (const char*)sm.wT[c & 1];
    #pragma unroll
    for (int ntl = 0; ntl < 8; ++ntl) {
      int nl = l15 + ntl * 16;
      int n  = c * 128 + nl;
      f32x4 cacc = fz;
      #pragma unroll
      for (int ks2 = 0; ks2 < 2; ++ks2) {
        uint32_t off = (uint32_t)(nl << 7) +
                       ((uint32_t)((g * 8 + ks2 * 32) << 1) ^ (uint32_t)((nl & 7) << 4));
        short8 wf = *(const short8*)(wtc + off);
        cacc = __builtin_amdgcn_mfma_f32_16x16x32_bf16(af[ks2], wf, cacc, 0, 0, 0);
      }
      float bv = bg[n];
      #pragma unroll
      for (int j = 0; j < 4; ++j) {
        int qr = orow + g4 + j;
        outg[((size_t)b * SEQ + qr) * DMODEL + n] = cacc[j] + bv;
      }
    }
  }
}

// ============================================================================
// Last-resort fallback (self-contained, no workspace): Round-2 kernel
// ============================================================================
struct F_SMemMain {
  unsigned short kt[KBLK * DK];
  unsigned short vt[DK * KBLK];
  unsigned short p[4][16 * KBLK];
};
struct F_SMemEpi {
  unsigned short wT[128 * DK];
  unsigned short ob[4][16 * DK];
};
union F_SMemU { F_SMemMain m; F_SMemEpi e; };

__global__ __launch_bounds__(NT, 2)
void attn_fc_fused_v1(const float* __restrict__ qg, const float* __restrict__ kg,
                      const float* __restrict__ vg, const float* __restrict__ wg,
                      const float* __restrict__ bg, float* __restrict__ outg) {
  __shared__ F_SMemU sm;
  const int b    = blockIdx.x;
  const int qb   = blockIdx.y;
  const int tid  = threadIdx.x;
  const int wid  = tid >> 6;
  const int lane = tid & 63;
  const int l15  = lane & 15;
  const int g    = lane >> 4;
  const int g4   = g << 2;

  short8 qf[2];
  {
    const float* qp = qg + ((size_t)b * SEQ + (size_t)(qb * QBLK + wid * 16 + l15)) * DK + g * 8;
    #pragma unroll
    for (int ks = 0; ks < 2; ++ks) {
      float4 a0 = *(const float4*)(qp + ks * 32);
      float4 a1 = *(const float4*)(qp + ks * 32 + 4);
      union { short8 v; uint32_t u[4]; } cv;
      cv.u[0] = pack2(a0.x, a0.y); cv.u[1] = pack2(a0.z, a0.w);
      cv.u[2] = pack2(a1.x, a1.y); cv.u[3] = pack2(a1.z, a1.w);
      qf[ks] = cv.v;
    }
  }
  const f32x4 fz = {0.f, 0.f, 0.f, 0.f};
  f32x4 oacc[4];
  #pragma unroll
  for (int i = 0; i < 4; ++i) oacc[i] = fz;
  float mrun[4], lrun[4];
  #pragma unroll
  for (int j = 0; j < 4; ++j) { mrun[j] = -1e30f; lrun[j] = 0.f; }
  const float SC = 0.125f * 1.44269504088896f;
  const float* kp0 = kg + (size_t)b * SEQ * DK;
  const float* vp0 = vg + (size_t)b * SEQ * DK;
  unsigned short* pbase = sm.m.p[wid];

  for (int t0 = 0; t0 < SEQ; t0 += KBLK) {
    __syncthreads();
    {
      const float* kp = kp0 + (size_t)t0 * DK;
      const float* vp = vp0 + (size_t)t0 * DK;
      #pragma unroll
      for (int r = 0; r < 4; ++r) {
        int f4  = r * 256 + tid;
        int key = f4 >> 4;
        int d0  = (f4 & 15) << 2;
        float4 kv = *(const float4*)(kp + f4 * 4);
        float4 vv = *(const float4*)(vp + f4 * 4);
        uint32_t koff = (uint32_t)(key << 7) +
                        ((uint32_t)(d0 << 1) ^ (uint32_t)((key & 7) << 4));
        *(uint2*)((char*)sm.m.kt + koff) = make_uint2(pack2(kv.x, kv.y), pack2(kv.z, kv.w));
        float vj[4] = {vv.x, vv.y, vv.z, vv.w};
        #pragma unroll
        for (int jj = 0; jj < 4; ++jj) {
          int d = d0 + jj;
          uint32_t voff = (uint32_t)(d << 7) +
                          ((uint32_t)(key << 1) ^ (uint32_t)((d & 7) << 4));
          *(unsigned short*)((char*)sm.m.vt + voff) = f2bf(vj[jj]);
        }
      }
    }
    __syncthreads();
    f32x4 s[4];
    #pragma unroll
    for (int t = 0; t < 4; ++t) s[t] = fz;
    #pragma unroll
    for (int ks = 0; ks < 2; ++ks) {
      #pragma unroll
      for (int t = 0; t < 4; ++t) {
        int key = l15 + t * 16;
        uint32_t off = (uint32_t)(key << 7) +
                       ((uint32_t)((g * 8 + ks * 32) << 1) ^ (uint32_t)((key & 7) << 4));
        short8 kf = *(const short8*)((const char*)sm.m.kt + off);
        s[t] = __builtin_amdgcn_mfma_f32_16x16x32_bf16(qf[ks], kf, s[t], 0, 0, 0);
      }
    }
    #pragma unroll
    for (int t = 0; t < 4; ++t)
      #pragma unroll
      for (int j = 0; j < 4; ++j) s[t][j] *= SC;
    float rsc[4], tsum[4];
    #pragma unroll
    for (int j = 0; j < 4; ++j) {
      float tm = fmaxf(fmaxf(s[0][j], s[1][j]), fmaxf(s[2][j], s[3][j]));
      #pragma unroll
      for (int off = 1; off < 16; off <<= 1) tm = fmaxf(tm, __shfl_xor(tm, off, 64));
      float nm = fmaxf(mrun[j], tm);
      rsc[j]  = exp2f(mrun[j] - nm);
      mrun[j] = nm;
      tsum[j] = 0.f;
    }
    #pragma unroll
    for (int t = 0; t < 4; ++t)
      #pragma unroll
      for (int j = 0; j < 4; ++j) {
        float e = exp2f(s[t][j] - mrun[j]);
        s[t][j] = e;
        tsum[j] += e;
      }
    #pragma unroll
    for (int j = 0; j < 4; ++j) {
      float ts = tsum[j];
      #pragma unroll
      for (int off = 1; off < 16; off <<= 1) ts += __shfl_xor(ts, off, 64);
      lrun[j] = lrun[j] * rsc[j] + ts;
    }
    #pragma unroll
    for (int dt = 0; dt < 4; ++dt)
      #pragma unroll
      for (int j = 0; j < 4; ++j) oacc[dt][j] *= rsc[j];
    #pragma unroll
    for (int t = 0; t < 4; ++t)
      #pragma unroll
      for (int j = 0; j < 4; ++j) {
        int row = g4 + j;
        int col = l15 + t * 16;
        uint32_t off = (uint32_t)(row << 7) +
                       ((uint32_t)(col << 1) ^ (uint32_t)((row & 7) << 4));
        *(unsigned short*)((char*)pbase + off) = f2bf(s[t][j]);
      }
    #pragma unroll
    for (int ks = 0; ks < 2; ++ks) {
      uint32_t aoff = (uint32_t)(l15 << 7) +
                      ((uint32_t)((g * 8 + ks * 32) << 1) ^ (uint32_t)((l15 & 7) << 4));
      short8 pa = *(const short8*)((const char*)pbase + aoff);
      #pragma unroll
      for (int dt = 0; dt < 4; ++dt) {
        int d = l15 + dt * 16;
        uint32_t boff = (uint32_t)(d << 7) +
                        ((uint32_t)((g * 8 + ks * 32) << 1) ^ (uint32_t)((d & 7) << 4));
        short8 vf = *(const short8*)((const char*)sm.m.vt + boff);
        oacc[dt] = __builtin_amdgcn_mfma_f32_16x16x32_bf16(pa, vf, oacc[dt], 0, 0, 0);
      }
    }
  }
  {
    float inv[4];
    #pragma unroll
    for (int j = 0; j < 4; ++j) inv[j] = 1.0f / lrun[j];
    unsigned short* obase = sm.e.ob[wid];
    #pragma unroll
    for (int dt = 0; dt < 4; ++dt)
      #pragma unroll
      for (int j = 0; j < 4; ++j) {
        int row = g4 + j;
        int col = l15 + dt * 16;
        uint32_t off = (uint32_t)(row << 7) +
                       ((uint32_t)(col << 1) ^ (uint32_t)((row & 7) << 4));
        *(unsigned short*)((char*)obase + off) = f2bf(oacc[dt][j] * inv[j]);
      }
    short8 af[2];
    #pragma unroll
    for (int ks = 0; ks < 2; ++ks) {
      uint32_t off = (uint32_t)(l15 << 7) +
                     ((uint32_t)((g * 8 + ks * 32) << 1) ^ (uint32_t)((l15 & 7) << 4));
      af[ks] = *(const short8*)((const char*)obase + off);
    }
    const int orow = qb * QBLK + wid * 16;
    #pragma unroll 1
    for (int nc = 0; nc < 4; ++nc) {
      __syncthreads();
      #pragma unroll
      for (int i = 0; i < 8; ++i) {
        int id = tid + i * 256;
        int n  = id & 127;
        int kk = (id >> 7) << 2;
        float w0 = wg[(kk + 0) * DMODEL + nc * 128 + n];
        float w1 = wg[(kk + 1) * DMODEL + nc * 128 + n];
        float w2 = wg[(kk + 2) * DMODEL + nc * 128 + n];
        float w3 = wg[(kk + 3) * DMODEL + nc * 128 + n];
        uint32_t off = (uint32_t)(n << 7) +
                       ((uint32_t)(kk << 1) ^ (uint32_t)((n & 7) << 4));
        *(uint2*)((char*)sm.e.wT + off) = make_uint2(pack2(w0, w1), pack2(w2, w3));
      }
      __syncthreads();
      #pragma unroll
      for (int ntl = 0; ntl < 8; ++ntl) {
        int nl = l15 + ntl * 16;
        int n  = nc * 128 + nl;
        f32x4 c = fz;
        #pragma unroll
        for (int ks = 0; ks < 2; ++ks) {
          uint32_t off = (uint32_t)(nl << 7) +
                         ((uint32_t)((g * 8 + ks * 32) << 1) ^ (uint32_t)((nl & 7) << 4));
          short8 wf = *(const short8*)((const char*)sm.e.wT + off);
          c = __builtin_amdgcn_mfma_f32_16x16x32_bf16(af[ks], wf, c, 0, 0, 0);
        }
        float bv = bg[n];
        #pragma unroll
        for (int j = 0; j < 4; ++j) {
          int qr = orow + g4 + j;
          outg[((size_t)b * SEQ + qr) * DMODEL + n] = c[j] + bv;
        }
      }
    }
  }
}

extern "C" void kernel_launch(void* const* d_in, const int* in_sizes, int n_in,
                              void* d_out, int out_size, void* d_ws, size_t ws_size,
                              hipStream_t stream) {
  (void)in_sizes; (void)n_in; (void)out_size;
  const float* q  = (const float*)d_in[0];
  const float* k  = (const float*)d_in[1];
  const float* v  = (const float*)d_in[2];
  const float* w  = (const float*)d_in[3];
  const float* bb = (const float*)d_in[4];
  float* out = (float*)d_out;
  unsigned char* ws = (unsigned char*)d_ws;
  if (ws_size >= WS_NEED3 && d_ws != nullptr) {
    preconv<<<dim3(2064), dim3(256), 0, stream>>>(k, v, w, ws);
    attn_split32<<<dim3(BATCH, SEQ / 128, 4), dim3(NT), 0, stream>>>(
        q, ws, (float*)(ws + POFF), (float*)(ws + LOFF4), 16);
    fc_combine<<<dim3(BATCH, SEQ / QBLK), dim3(NT), 0, stream>>>(
        (const float*)(ws + POFF), (const float*)(ws + LOFF4), ws, bb, out, 4);
  } else if (ws_size >= WS_NEED2 && d_ws != nullptr) {
    preconv<<<dim3(2064), dim3(256), 0, stream>>>(k, v, w, ws);
    attn_split32<<<dim3(BATCH, SEQ / 128, 2), dim3(NT), 0, stream>>>(
        q, ws, (float*)(ws + POFF), (float*)(ws + LOFF2), 32);
    fc_combine<<<dim3(BATCH, SEQ / QBLK), dim3(NT), 0, stream>>>(
        (const float*)(ws + POFF), (const float*)(ws + LOFF2), ws, bb, out, 2);
  } else {
    attn_fc_fused_v1<<<dim3(BATCH, SEQ / QBLK), dim3(NT), 0, stream>>>(q, k, v, w, bb, out);
  }
}

// Round 12
// 77.920 us; speedup vs baseline: 1.2102x; 1.2102x over previous
//
#include <hip/hip_runtime.h>
#include <hip/hip_bf16.h>
#include <stdint.h>

#define BATCH  8
#define SEQ    4096
#define DK     64
#define DMODEL 512
#define QBLK   64
#define KBLK   64
#define NT     256

#define KWS_OFF   0u
#define VWS_OFF   4194304u
#define WWS_OFF   8388608u
#define WS_NEED   8454144u
#define POFF      8454144u
// split-K x2 (R8 layout): opart 2*8*4096*64*4 = 16777216, lpart 2*8*4096*4
#define LOFF2     (POFF + 16777216u)
#define WS_NEED2  (LOFF2 + 262144u)

typedef __attribute__((ext_vector_type(8)))  short short8;
typedef __attribute__((ext_vector_type(4)))  float f32x4;
typedef __attribute__((ext_vector_type(16))) float f32x16;

__device__ __forceinline__ unsigned short f2bf(float x) {
  uint32_t u = __builtin_bit_cast(uint32_t, x);
  u += 0x7FFFu + ((u >> 16) & 1u);          // RNE
  return (unsigned short)(u >> 16);
}
__device__ __forceinline__ uint32_t pack2(float a, float b) {
  return (uint32_t)f2bf(a) | ((uint32_t)f2bf(b) << 16);
}
__device__ __forceinline__ uint32_t cvtpk2(float a, float b) {
  __hip_bfloat162 h = __float22bfloat162_rn(make_float2(a, b)); // v_cvt_pk_bf16_f32
  uint32_t r;
  __builtin_memcpy(&r, &h, 4);
  return r;
}
__device__ __forceinline__ void async16(void* lds, const void* g) {
  __builtin_amdgcn_global_load_lds(
      (const __attribute__((address_space(1))) uint32_t*)g,
      (__attribute__((address_space(3))) uint32_t*)lds, 16, 0, 0);
}

// ============================================================================
// Pre-pass (EXACT R8, hardware-verified): K -> bf16 swizzled tile images,
// V -> bf16 transposed swizzled tile images, W -> bf16 W^T chunk images.
// ============================================================================
__global__ __launch_bounds__(256)
void preconv(const float* __restrict__ kg_, const float* __restrict__ vg_,
             const float* __restrict__ wg_, unsigned char* __restrict__ ws) {
  int id = blockIdx.x * 256 + threadIdx.x;
  unsigned char* kws = ws + KWS_OFF;
  unsigned char* vws = ws + VWS_OFF;
  unsigned char* wws = ws + WWS_OFF;
  if (id < 262144) {
    int dg = id & 7, key = (id >> 3) & 63, t = (id >> 9) & 63, b = id >> 15;
    const float* src = kg_ + (((size_t)(b * 4096 + t * 64 + key)) << 6) + dg * 8;
    float4 a0 = *(const float4*)src;
    float4 a1 = *(const float4*)(src + 4);
    uint4 o;
    o.x = pack2(a0.x, a0.y); o.y = pack2(a0.z, a0.w);
    o.z = pack2(a1.x, a1.y); o.w = pack2(a1.z, a1.w);
    *(uint4*)(kws + (((size_t)(b * 64 + t)) << 13) +
              (uint32_t)(key * 128 + ((dg * 16) ^ ((key & 7) << 4)))) = o;
  } else if (id < 524288) {
    int iv = id - 262144;
    int kg2 = iv & 7, d = (iv >> 3) & 63, t = (iv >> 9) & 63, b = iv >> 15;
    const float* src = vg_ + (((size_t)(b * 4096 + t * 64 + kg2 * 8)) << 6) + d;
    float m[8];
    #pragma unroll
    for (int i = 0; i < 8; ++i) m[i] = src[i * 64];
    uint4 o;
    o.x = pack2(m[0], m[1]); o.y = pack2(m[2], m[3]);
    o.z = pack2(m[4], m[5]); o.w = pack2(m[6], m[7]);
    *(uint4*)(vws + (((size_t)(b * 64 + t)) << 13) +
              (uint32_t)(d * 128 + ((kg2 * 16) ^ ((d & 7) << 4)))) = o;
  } else if (id < 528384) {
    int iw = id - 524288;
    int kg2 = iw & 7, n = (iw >> 3) & 127, c = iw >> 10;
    const float* src = wg_ + (size_t)(kg2 * 8) * DMODEL + c * 128 + n;
    float m[8];
    #pragma unroll
    for (int i = 0; i < 8; ++i) m[i] = src[i * DMODEL];
    uint4 o;
    o.x = pack2(m[0], m[1]); o.y = pack2(m[2], m[3]);
    o.z = pack2(m[4], m[5]); o.w = pack2(m[6], m[7]);
    *(uint4*)(wws + c * 16384 + (uint32_t)(n * 128 + ((kg2 * 16) ^ ((n & 7) << 4)))) = o;
  }
}

// ============================================================================
// Split-K attention (EXACT R8 body; single change vs R8: exp2f ->
// __builtin_amdgcn_exp2f, exonerated by the R9/R10 bisection).
// 32x32 MFMA, swapped QK^T, P fully in registers via cvt_pk + permlane32_swap.
// grid (8, 32, 2); block z covers `ntiles`=32 K-tiles.
// ============================================================================
struct SMemA32 { unsigned char kt[2][8192]; unsigned char vt[2][8192]; };
static_assert(sizeof(SMemA32) == 32768, "LDS layout");

__global__ __launch_bounds__(NT, 2)
void attn_split32(const float* __restrict__ qg, const unsigned char* __restrict__ ws,
                  float* __restrict__ opart, float* __restrict__ lpart, int ntiles) {
  __shared__ SMemA32 sm;
  const int b    = blockIdx.x;      // batch -> XCD (linear id % 8 == b)
  const int qb   = blockIdx.y;
  const int z    = blockIdx.z;      // K-split slice
  const int tid  = threadIdx.x;
  const int wid  = tid >> 6;
  const int lane = tid & 63;
  const int l31  = lane & 31;
  const int hi   = lane >> 5;

  const unsigned char* kws = ws + KWS_OFF;
  const unsigned char* vws = ws + VWS_OFF;
  const int    wstg  = wid << 11;          // each wave stages 2KB of each tile
  const int    ln16  = lane << 4;
  const size_t tbase = ((size_t)(b * 64)) << 13;
  const int    tt0   = z * ntiles;

  const float SC = 0.125f * 1.44269504088896f;   // scale * log2(e)

  // ---- Q^T B-fragments (B: k=d=(ds*16 + hi*8 + e), col=q=l31), scaled ----
  const int qrow = qb * 128 + wid * 32 + l31;
  short8 qf[4];
  {
    const float* qp = qg + ((size_t)b * SEQ + qrow) * DK;
    #pragma unroll
    for (int ds = 0; ds < 4; ++ds) {
      const float* p = qp + ds * 16 + hi * 8;
      float4 a0 = *(const float4*)p;
      float4 a1 = *(const float4*)(p + 4);
      union { short8 v; uint32_t u[4]; } cv;
      cv.u[0] = cvtpk2(a0.x * SC, a0.y * SC); cv.u[1] = cvtpk2(a0.z * SC, a0.w * SC);
      cv.u[2] = cvtpk2(a1.x * SC, a1.y * SC); cv.u[3] = cvtpk2(a1.z * SC, a1.w * SC);
      qf[ds] = cv.v;
    }
  }

  f32x16 o0, o1;
  #pragma unroll
  for (int r = 0; r < 16; ++r) { o0[r] = 0.f; o1[r] = 0.f; }
  float lsum = 0.f;

#define STG32(buf, tt) do { \
    const unsigned char* ks_ = kws + tbase + (((size_t)(tt)) << 13); \
    const unsigned char* vs_ = vws + tbase + (((size_t)(tt)) << 13); \
    async16(sm.kt[buf] + wstg,        ks_ + wstg + ln16); \
    async16(sm.kt[buf] + wstg + 1024, ks_ + wstg + 1024 + ln16); \
    async16(sm.vt[buf] + wstg,        vs_ + wstg + ln16); \
    async16(sm.vt[buf] + wstg + 1024, vs_ + wstg + 1024 + ln16); \
  } while (0)

  STG32(0, tt0);
  int cur = 0;
  #pragma unroll 1
  for (int t = 0; t < ntiles; ++t) {
    __syncthreads();                 // buf[cur] staged; all waves past buf[cur^1] reads
    if (t + 1 < ntiles) STG32(cur ^ 1, tt0 + t + 1);

    const char* ktc = (const char*)sm.kt[cur];
    const char* vtc = (const char*)sm.vt[cur];

    // ---- swapped QK^T: sT[kh] = K[kh*32+..] . Q^T  (keys in regs, q on lanes)
    f32x16 s0, s1;
    #pragma unroll
    for (int r = 0; r < 16; ++r) { s0[r] = 0.f; s1[r] = 0.f; }
    #pragma unroll
    for (int ds = 0; ds < 4; ++ds) {
      uint32_t cb   = (uint32_t)(ds * 32 + hi * 16);     // d-byte base
      uint32_t swz  = (uint32_t)((l31 & 7) << 4);
      uint32_t off0 = ((uint32_t)l31 << 7)        + (cb ^ swz);
      uint32_t off1 = ((uint32_t)(32 + l31) << 7) + (cb ^ swz);
      short8 ka0 = *(const short8*)(ktc + off0);
      short8 ka1 = *(const short8*)(ktc + off1);
      s0 = __builtin_amdgcn_mfma_f32_32x32x16_bf16(ka0, qf[ds], s0, 0, 0, 0);
      s1 = __builtin_amdgcn_mfma_f32_32x32x16_bf16(ka1, qf[ds], s1, 0, 0, 0);
    }

    // ---- P = exp2(S) via bare v_exp_f32 (2^x); per-lane row sums ----
    #pragma unroll
    for (int r = 0; r < 16; ++r) {
      s0[r] = __builtin_amdgcn_exp2f(s0[r]); lsum += s0[r];
      s1[r] = __builtin_amdgcn_exp2f(s1[r]); lsum += s1[r];
    }

    // ---- PV: per 16-key slice ks, build A-frag in-register, 2 d-halves ----
    #pragma unroll
    for (int ks = 0; ks < 4; ++ks) {
      int ss = ks & 1;
      uint32_t A0, A1, B0, B1;
      if (ks < 2) {
        A0 = cvtpk2(s0[8 * ss + 0], s0[8 * ss + 1]);
        A1 = cvtpk2(s0[8 * ss + 2], s0[8 * ss + 3]);
        B0 = cvtpk2(s0[8 * ss + 4], s0[8 * ss + 5]);
        B1 = cvtpk2(s0[8 * ss + 6], s0[8 * ss + 7]);
      } else {
        A0 = cvtpk2(s1[8 * ss + 0], s1[8 * ss + 1]);
        A1 = cvtpk2(s1[8 * ss + 2], s1[8 * ss + 3]);
        B0 = cvtpk2(s1[8 * ss + 4], s1[8 * ss + 5]);
        B1 = cvtpk2(s1[8 * ss + 6], s1[8 * ss + 7]);
      }
      // dst hi-lanes <-> src lo-lanes: yields frag dwords (0,2) and (1,3)
      asm("v_permlane32_swap_b32 %0, %1" : "+v"(A0), "+v"(B0));
      asm("v_permlane32_swap_b32 %0, %1" : "+v"(A1), "+v"(B1));
      union { short8 v; uint32_t u[4]; } pa;
      pa.u[0] = A0; pa.u[1] = A1; pa.u[2] = B0; pa.u[3] = B1;

      uint32_t kb = (uint32_t)(ks * 32 + hi * 16);       // key-byte base
      {
        int d = l31;
        uint32_t off = ((uint32_t)d << 7) + (kb ^ ((uint32_t)(d & 7) << 4));
        short8 vf = *(const short8*)(vtc + off);
        o0 = __builtin_amdgcn_mfma_f32_32x32x16_bf16(pa.v, vf, o0, 0, 0, 0);
      }
      {
        int d = 32 + l31;
        uint32_t off = ((uint32_t)d << 7) + (kb ^ ((uint32_t)(d & 7) << 4));
        short8 vf = *(const short8*)(vtc + off);
        o1 = __builtin_amdgcn_mfma_f32_32x32x16_bf16(pa.v, vf, o1, 0, 0, 0);
      }
    }
    cur ^= 1;
  }

  // ---- partials: O rows in regs (q=(r&3)+8*(r>>2)+4*hi), d on lanes ----
  float lt = lsum + __shfl_xor(lsum, 32, 64);   // both key-halves of q=l31
  const size_t rbase = (size_t)(z * 8 + b) * 4096 + (size_t)(qb * 128 + wid * 32);
  float* op = opart + rbase * 64;
  #pragma unroll
  for (int r = 0; r < 16; ++r) {
    int qloc = (r & 3) + 8 * (r >> 2) + 4 * hi;
    op[(size_t)qloc * 64 + l31]      = o0[r];
    op[(size_t)qloc * 64 + 32 + l31] = o1[r];
  }
  if (hi == 0) lpart[rbase + l31] = lt;
}

// ============================================================================
// Combine + FC kernel: grid (8, 64). Sums nz K-split partials, normalizes,
// then O[64x64] @ W[64x512] + b with dbuf W staging.
// ============================================================================
struct SMemComb {
  unsigned char  wT[2][16384];     // W^T chunk images (dbuf)
  unsigned short ob[4][1024];      // per-wave normalized O [16][64] bf16, swz
};
static_assert(sizeof(SMemComb) == 40960, "LDS layout");

__global__ __launch_bounds__(NT, 2)
void fc_combine(const float* __restrict__ opart, const float* __restrict__ lpart,
                const unsigned char* __restrict__ ws, const float* __restrict__ bg,
                float* __restrict__ outg, int nz) {
  __shared__ SMemComb sm;
  const int b    = blockIdx.x;
  const int qb   = blockIdx.y;
  const int tid  = threadIdx.x;
  const int wid  = tid >> 6;
  const int lane = tid & 63;
  const int l15  = lane & 15;
  const int g    = lane >> 4;
  const int g4   = g << 2;

  const unsigned char* wws = ws + WWS_OFF;
  const int wb   = wid << 10;
  const int ln16 = lane << 4;

  const f32x4 fz = {0.f, 0.f, 0.f, 0.f};

  float inv[4];
  #pragma unroll
  for (int j = 0; j < 4; ++j) {
    int row = wid * 16 + g4 + j;
    float ls = 0.f;
    #pragma unroll 1
    for (int zz = 0; zz < nz; ++zz)
      ls += lpart[(size_t)(zz * 8 + b) * 4096 + qb * 64 + row];
    inv[j] = 1.0f / ls;
  }
  unsigned short* obase = sm.ob[wid];
  #pragma unroll
  for (int dt = 0; dt < 4; ++dt)
    #pragma unroll
    for (int j = 0; j < 4; ++j) {
      int row  = wid * 16 + g4 + j;
      int col  = l15 + dt * 16;
      float o = 0.f;
      #pragma unroll 1
      for (int zz = 0; zz < nz; ++zz)
        o += opart[((size_t)(zz * 8 + b) * 4096 + qb * 64 + row) * 64 + col];
      o *= inv[j];
      int rloc = g4 + j;
      uint32_t off = (uint32_t)(rloc << 7) +
                     ((uint32_t)(col << 1) ^ (uint32_t)((rloc & 7) << 4));
      *(unsigned short*)((char*)obase + off) = f2bf(o);
    }
  short8 af[2];
  #pragma unroll
  for (int ks2 = 0; ks2 < 2; ++ks2) {
    uint32_t off = (uint32_t)(l15 << 7) +
                   ((uint32_t)((g * 8 + ks2 * 32) << 1) ^ (uint32_t)((l15 & 7) << 4));
    af[ks2] = *(const short8*)((const char*)obase + off);
  }

#define STAGE_W(buf, cc) do { \
    const unsigned char* wsrc = wws + (uint32_t)(cc) * 16384u; \
    async16(sm.wT[buf] + wb,         wsrc + wb + ln16); \
    async16(sm.wT[buf] + wb + 4096,  wsrc + wb + 4096 + ln16); \
    async16(sm.wT[buf] + wb + 8192,  wsrc + wb + 8192 + ln16); \
    async16(sm.wT[buf] + wb + 12288, wsrc + wb + 12288 + ln16); \
  } while (0)

  STAGE_W(0, 0);
  const int orow = qb * QBLK + wid * 16;
  #pragma unroll 1
  for (int c = 0; c < 4; ++c) {
    __syncthreads();               // wT[c&1] ready; prev reads of other buf done
    if (c + 1 < 4) STAGE_W((c + 1) & 1, c + 1);
    const char* wtc = (const char*)sm.wT[c & 1];
    #pragma unroll
    for (int ntl = 0; ntl < 8; ++ntl) {
      int nl = l15 + ntl * 16;
      int n  = c * 128 + nl;
      f32x4 cacc = fz;
      #pragma unroll
      for (int ks2 = 0; ks2 < 2; ++ks2) {
        uint32_t off = (uint32_t)(nl << 7) +
                       ((uint32_t)((g * 8 + ks2 * 32) << 1) ^ (uint32_t)((nl & 7) << 4));
        short8 wf = *(const short8*)(wtc + off);
        cacc = __builtin_amdgcn_mfma_f32_16x16x32_bf16(af[ks2], wf, cacc, 0, 0, 0);
      }
      float bv = bg[n];
      #pragma unroll
      for (int j = 0; j < 4; ++j) {
        int qr = orow + g4 + j;
        outg[((size_t)b * SEQ + qr) * DMODEL + n] = cacc[j] + bv;
      }
    }
  }
}

// ============================================================================
// Last-resort fallback (self-contained, no workspace): Round-2 kernel
// ============================================================================
struct F_SMemMain {
  unsigned short kt[KBLK * DK];
  unsigned short vt[DK * KBLK];
  unsigned short p[4][16 * KBLK];
};
struct F_SMemEpi {
  unsigned short wT[128 * DK];
  unsigned short ob[4][16 * DK];
};
union F_SMemU { F_SMemMain m; F_SMemEpi e; };

__global__ __launch_bounds__(NT, 2)
void attn_fc_fused_v1(const float* __restrict__ qg, const float* __restrict__ kg,
                      const float* __restrict__ vg, const float* __restrict__ wg,
                      const float* __restrict__ bg, float* __restrict__ outg) {
  __shared__ F_SMemU sm;
  const int b    = blockIdx.x;
  const int qb   = blockIdx.y;
  const int tid  = threadIdx.x;
  const int wid  = tid >> 6;
  const int lane = tid & 63;
  const int l15  = lane & 15;
  const int g    = lane >> 4;
  const int g4   = g << 2;

  short8 qf[2];
  {
    const float* qp = qg + ((size_t)b * SEQ + (size_t)(qb * QBLK + wid * 16 + l15)) * DK + g * 8;
    #pragma unroll
    for (int ks = 0; ks < 2; ++ks) {
      float4 a0 = *(const float4*)(qp + ks * 32);
      float4 a1 = *(const float4*)(qp + ks * 32 + 4);
      union { short8 v; uint32_t u[4]; } cv;
      cv.u[0] = pack2(a0.x, a0.y); cv.u[1] = pack2(a0.z, a0.w);
      cv.u[2] = pack2(a1.x, a1.y); cv.u[3] = pack2(a1.z, a1.w);
      qf[ks] = cv.v;
    }
  }
  const f32x4 fz = {0.f, 0.f, 0.f, 0.f};
  f32x4 oacc[4];
  #pragma unroll
  for (int i = 0; i < 4; ++i) oacc[i] = fz;
  float mrun[4], lrun[4];
  #pragma unroll
  for (int j = 0; j < 4; ++j) { mrun[j] = -1e30f; lrun[j] = 0.f; }
  const float SC = 0.125f * 1.44269504088896f;
  const float* kp0 = kg + (size_t)b * SEQ * DK;
  const float* vp0 = vg + (size_t)b * SEQ * DK;
  unsigned short* pbase = sm.m.p[wid];

  for (int t0 = 0; t0 < SEQ; t0 += KBLK) {
    __syncthreads();
    {
      const float* kp = kp0 + (size_t)t0 * DK;
      const float* vp = vp0 + (size_t)t0 * DK;
      #pragma unroll
      for (int r = 0; r < 4; ++r) {
        int f4  = r * 256 + tid;
        int key = f4 >> 4;
        int d0  = (f4 & 15) << 2;
        float4 kv = *(const float4*)(kp + f4 * 4);
        float4 vv = *(const float4*)(vp + f4 * 4);
        uint32_t koff = (uint32_t)(key << 7) +
                        ((uint32_t)(d0 << 1) ^ (uint32_t)((key & 7) << 4));
        *(uint2*)((char*)sm.m.kt + koff) = make_uint2(pack2(kv.x, kv.y), pack2(kv.z, kv.w));
        float vj[4] = {vv.x, vv.y, vv.z, vv.w};
        #pragma unroll
        for (int jj = 0; jj < 4; ++jj) {
          int d = d0 + jj;
          uint32_t voff = (uint32_t)(d << 7) +
                          ((uint32_t)(key << 1) ^ (uint32_t)((d & 7) << 4));
          *(unsigned short*)((char*)sm.m.vt + voff) = f2bf(vj[jj]);
        }
      }
    }
    __syncthreads();
    f32x4 s[4];
    #pragma unroll
    for (int t = 0; t < 4; ++t) s[t] = fz;
    #pragma unroll
    for (int ks = 0; ks < 2; ++ks) {
      #pragma unroll
      for (int t = 0; t < 4; ++t) {
        int key = l15 + t * 16;
        uint32_t off = (uint32_t)(key << 7) +
                       ((uint32_t)((g * 8 + ks * 32) << 1) ^ (uint32_t)((key & 7) << 4));
        short8 kf = *(const short8*)((const char*)sm.m.kt + off);
        s[t] = __builtin_amdgcn_mfma_f32_16x16x32_bf16(qf[ks], kf, s[t], 0, 0, 0);
      }
    }
    #pragma unroll
    for (int t = 0; t < 4; ++t)
      #pragma unroll
      for (int j = 0; j < 4; ++j) s[t][j] *= SC;
    float rsc[4], tsum[4];
    #pragma unroll
    for (int j = 0; j < 4; ++j) {
      float tm = fmaxf(fmaxf(s[0][j], s[1][j]), fmaxf(s[2][j], s[3][j]));
      #pragma unroll
      for (int off = 1; off < 16; off <<= 1) tm = fmaxf(tm, __shfl_xor(tm, off, 64));
      float nm = fmaxf(mrun[j], tm);
      rsc[j]  = exp2f(mrun[j] - nm);
      mrun[j] = nm;
      tsum[j] = 0.f;
    }
    #pragma unroll
    for (int t = 0; t < 4; ++t)
      #pragma unroll
      for (int j = 0; j < 4; ++j) {
        float e = exp2f(s[t][j] - mrun[j]);
        s[t][j] = e;
        tsum[j] += e;
      }
    #pragma unroll
    for (int j = 0; j < 4; ++j) {
      float ts = tsum[j];
      #pragma unroll
      for (int off = 1; off < 16; off <<= 1) ts += __shfl_xor(ts, off, 64);
      lrun[j] = lrun[j] * rsc[j] + ts;
    }
    #pragma unroll
    for (int dt = 0; dt < 4; ++dt)
      #pragma unroll
      for (int j = 0; j < 4; ++j) oacc[dt][j] *= rsc[j];
    #pragma unroll
    for (int t = 0; t < 4; ++t)
      #pragma unroll
      for (int j = 0; j < 4; ++j) {
        int row = g4 + j;
        int col = l15 + t * 16;
        uint32_t off = (uint32_t)(row << 7) +
                       ((uint32_t)(col << 1) ^ (uint32_t)((row & 7) << 4));
        *(unsigned short*)((char*)pbase + off) = f2bf(s[t][j]);
      }
    #pragma unroll
    for (int ks = 0; ks < 2; ++ks) {
      uint32_t aoff = (uint32_t)(l15 << 7) +
                      ((uint32_t)((g * 8 + ks * 32) << 1) ^ (uint32_t)((l15 & 7) << 4));
      short8 pa = *(const short8*)((const char*)pbase + aoff);
      #pragma unroll
      for (int dt = 0; dt < 4; ++dt) {
        int d = l15 + dt * 16;
        uint32_t boff = (uint32_t)(d << 7) +
                        ((uint32_t)((g * 8 + ks * 32) << 1) ^ (uint32_t)((d & 7) << 4));
        short8 vf = *(const short8*)((const char*)sm.m.vt + boff);
        oacc[dt] = __builtin_amdgcn_mfma_f32_16x16x32_bf16(pa, vf, oacc[dt], 0, 0, 0);
      }
    }
  }
  {
    float inv[4];
    #pragma unroll
    for (int j = 0; j < 4; ++j) inv[j] = 1.0f / lrun[j];
    unsigned short* obase = sm.e.ob[wid];
    #pragma unroll
    for (int dt = 0; dt < 4; ++dt)
      #pragma unroll
      for (int j = 0; j < 4; ++j) {
        int row = g4 + j;
        int col = l15 + dt * 16;
        uint32_t off = (uint32_t)(row << 7) +
                       ((uint32_t)(col << 1) ^ (uint32_t)((row & 7) << 4));
        *(unsigned short*)((char*)obase + off) = f2bf(oacc[dt][j] * inv[j]);
      }
    short8 af[2];
    #pragma unroll
    for (int ks = 0; ks < 2; ++ks) {
      uint32_t off = (uint32_t)(l15 << 7) +
                     ((uint32_t)((g * 8 + ks * 32) << 1) ^ (uint32_t)((l15 & 7) << 4));
      af[ks] = *(const short8*)((const char*)obase + off);
    }
    const int orow = qb * QBLK + wid * 16;
    #pragma unroll 1
    for (int nc = 0; nc < 4; ++nc) {
      __syncthreads();
      #pragma unroll
      for (int i = 0; i < 8; ++i) {
        int id = tid + i * 256;
        int n  = id & 127;
        int kk = (id >> 7) << 2;
        float w0 = wg[(kk + 0) * DMODEL + nc * 128 + n];
        float w1 = wg[(kk + 1) * DMODEL + nc * 128 + n];
        float w2 = wg[(kk + 2) * DMODEL + nc * 128 + n];
        float w3 = wg[(kk + 3) * DMODEL + nc * 128 + n];
        uint32_t off = (uint32_t)(n << 7) +
                       ((uint32_t)(kk << 1) ^ (uint32_t)((n & 7) << 4));
        *(uint2*)((char*)sm.e.wT + off) = make_uint2(pack2(w0, w1), pack2(w2, w3));
      }
      __syncthreads();
      #pragma unroll
      for (int ntl = 0; ntl < 8; ++ntl) {
        int nl = l15 + ntl * 16;
        int n  = nc * 128 + nl;
        f32x4 c = fz;
        #pragma unroll
        for (int ks = 0; ks < 2; ++ks) {
          uint32_t off = (uint32_t)(nl << 7) +
                         ((uint32_t)((g * 8 + ks * 32) << 1) ^ (uint32_t)((nl & 7) << 4));
          short8 wf = *(const short8*)((const char*)sm.e.wT + off);
          c = __builtin_amdgcn_mfma_f32_16x16x32_bf16(af[ks], wf, c, 0, 0, 0);
        }
        float bv = bg[n];
        #pragma unroll
        for (int j = 0; j < 4; ++j) {
          int qr = orow + g4 + j;
          outg[((size_t)b * SEQ + qr) * DMODEL + n] = c[j] + bv;
        }
      }
    }
  }
}

extern "C" void kernel_launch(void* const* d_in, const int* in_sizes, int n_in,
                              void* d_out, int out_size, void* d_ws, size_t ws_size,
                              hipStream_t stream) {
  (void)in_sizes; (void)n_in; (void)out_size;
  const float* q  = (const float*)d_in[0];
  const float* k  = (const float*)d_in[1];
  const float* v  = (const float*)d_in[2];
  const float* w  = (const float*)d_in[3];
  const float* bb = (const float*)d_in[4];
  float* out = (float*)d_out;
  unsigned char* ws = (unsigned char*)d_ws;
  if (ws_size >= WS_NEED2 && d_ws != nullptr) {
    preconv<<<dim3(2064), dim3(256), 0, stream>>>(k, v, w, ws);
    attn_split32<<<dim3(BATCH, SEQ / 128, 2), dim3(NT), 0, stream>>>(
        q, ws, (float*)(ws + POFF), (float*)(ws + LOFF2), 32);
    fc_combine<<<dim3(BATCH, SEQ / QBLK), dim3(NT), 0, stream>>>(
        (const float*)(ws + POFF), (const float*)(ws + LOFF2), ws, bb, out, 2);
  } else {
    attn_fc_fused_v1<<<dim3(BATCH, SEQ / QBLK), dim3(NT), 0, stream>>>(q, k, v, w, bb, out);
  }
}